// Round 1
// baseline (371.140 us; speedup 1.0000x reference)
//
#include <hip/hip_runtime.h>
#include <stdint.h>

// ---------------------------------------------------------------------------
// SparseResUQueryNet: bitmap+rank sparse conv -> time max-pool -> sparse conv
//
// Round-9 = round-8 + 9-lane stencil probing:
//   - 3x3x3 taps probed by 9 lanes (one per (dx,dy) column): ONE bm word
//     covers the dz in {-1,0,+1} bit-triple (rare 2nd word on boundary
//     crossing, ~3%). Probe lane-requests/point: 54 -> ~10.
//   - rank (and hf) loaded ONLY for hit taps (2-6% of lanes) instead of
//     unconditionally — kills the 16.8MB hist_rank HBM stream in bb_pool.
//   - pooled no longer memset (41MB): only multi-contributor slots need
//     zero-init for CAS-max; tiny zero_multi_kernel handles those (~10k).
//   - everything else (split bm/rank, bf16 monotone-packed pooled, no query
//     sort, no LDS W staging) carried over from round-8.
// ---------------------------------------------------------------------------

#define TPB 256
#define SCAN_WPT 8
typedef unsigned long long u64;
typedef unsigned int u32;
typedef unsigned short u16;

// f32 -> RNE bf16 -> monotone u16 (order-preserving; 0 is below all reals)
__device__ __forceinline__ u32 trans16(float x) {
    u32 b = __float_as_uint(x);
    u32 bf = (b + 0x7FFFu + ((b >> 16) & 1u)) >> 16;
    return ((bf & 0x8000u) ? (~bf) : (bf | 0x8000u)) & 0xFFFFu;
}
__device__ __forceinline__ float detrans16(u32 u) {
    u32 orig = (u & 0x8000u) ? (u & 0x7FFFu) : ((~u) & 0xFFFFu);
    return __uint_as_float(orig << 16);
}

// K1: set existence bits; second pool contributor marks multi ----------------
__global__ void build_bitmaps_kernel(const int4* __restrict__ hc,
                                     const int* __restrict__ hb,
                                     int n,
                                     u64* __restrict__ hist_bm,
                                     u64* __restrict__ pool_bm,
                                     u64* __restrict__ multi_bm) {
    int j = blockIdx.x * blockDim.x + threadIdx.x;
    if (j >= n) return;
    int4 c = hc[j];                                   // (t,x,y,z)
    int key = ((c.x * 256 + c.y) * 256 + c.z) * 256 + c.w;
    atomicOr(&hist_bm[key >> 6], 1ull << (key & 63));
    int pk = ((hb[j] * 256 + c.y) * 256 + c.z) * 256 + c.w;
    u64 bit = 1ull << (pk & 63);
    u64 old = atomicOr(&pool_bm[pk >> 6], bit);
    if (old & bit) atomicOr(&multi_bm[pk >> 6], bit); // >=2 contributors
}

// scan stage 1: per-block popcount sums --------------------------------------
__global__ void scan_sum_kernel(const u64* __restrict__ bm, u32* __restrict__ bsum) {
    __shared__ u32 s[TPB];
    int t = threadIdx.x;
    size_t base = ((size_t)blockIdx.x * TPB + t) * SCAN_WPT;
    u32 acc = 0;
#pragma unroll
    for (int i = 0; i < SCAN_WPT; i++) acc += __popcll(bm[base + i]);
    s[t] = acc; __syncthreads();
    for (int off = TPB / 2; off > 0; off >>= 1) {
        if (t < off) s[t] += s[t + off];
        __syncthreads();
    }
    if (t == 0) bsum[blockIdx.x] = s[0];
}

// scan stage 2: exclusive scan of block sums (count <= 2048), one block ------
__global__ void scan_partials_kernel(u32* __restrict__ bsum, int count) {
    __shared__ u32 s[TPB];
    int t = threadIdx.x;
    int wpt = count >> 8;                              // 8 (hist) or 1 (pool)
    u32 v[8]; u32 acc = 0;
    for (int i = 0; i < wpt; i++) { v[i] = bsum[t * wpt + i]; acc += v[i]; }
    s[t] = acc; __syncthreads();
    for (int off = 1; off < TPB; off <<= 1) {          // inclusive Hillis-Steele
        u32 x = (t >= off) ? s[t - off] : 0;
        __syncthreads();
        s[t] += x;
        __syncthreads();
    }
    u32 run = s[t] - acc;                              // exclusive base
    for (int i = 0; i < wpt; i++) { bsum[t * wpt + i] = run; run += v[i]; }
}

// scan stage 3: per-word exclusive rank --------------------------------------
__global__ void scan_apply_kernel(const u64* __restrict__ bm,
                                  const u32* __restrict__ bsum,
                                  u32* __restrict__ rank) {
    __shared__ u32 s[TPB];
    int t = threadIdx.x;
    size_t base = ((size_t)blockIdx.x * TPB + t) * SCAN_WPT;
    u32 pc[SCAN_WPT]; u32 acc = 0;
#pragma unroll
    for (int i = 0; i < SCAN_WPT; i++) { pc[i] = __popcll(bm[base + i]); acc += pc[i]; }
    s[t] = acc; __syncthreads();
    for (int off = 1; off < TPB; off <<= 1) {
        u32 x = (t >= off) ? s[t - off] : 0;
        __syncthreads();
        s[t] += x;
        __syncthreads();
    }
    u32 run = bsum[blockIdx.x] + s[t] - acc;
#pragma unroll
    for (int i = 0; i < SCAN_WPT; i++) { rank[base + i] = run; run += pc[i]; }
}

// zero only the pooled rows that will take the CAS-max path ------------------
__global__ void zero_multi_kernel(const u64* __restrict__ multi_bm,
                                  const u64* __restrict__ pool_bm,
                                  const u32* __restrict__ pool_rank,
                                  u32* __restrict__ pooled) {
    int wI = blockIdx.x * blockDim.x + threadIdx.x;    // word index < NW_P
    u64 mw = multi_bm[wI];
    if (!mw) return;
    u64 pw = pool_bm[wI];
    u32 rb = pool_rank[wI];
    while (mw) {
        int b = __ffsll((long long)mw) - 1;
        mw &= mw - 1;
        u32 slot = rb + (u32)__popcll(pw & ((1ull << b) - 1ull));
        u32* row = pooled + (size_t)slot * 16;
#pragma unroll
        for (int i = 0; i < 16; i++) row[i] = 0u;
    }
}

// K2: half-wave per voxel: 27-tap conv (1->32) via 9-lane probe --------------
__global__ void bb_pool_kernel(const int4* __restrict__ hc,
                               const int* __restrict__ hb,
                               const float* __restrict__ hf,
                               const float* __restrict__ Wbb,   // [27*32]
                               int n,
                               const u64* __restrict__ hist_bm,
                               const u32* __restrict__ hist_rank,
                               const u64* __restrict__ pool_bm,
                               const u32* __restrict__ pool_rank,
                               const u64* __restrict__ multi_bm,
                               u32* __restrict__ pooled) {
    int p = (blockIdx.x * blockDim.x + threadIdx.x) >> 5;   // voxel index
    if (p >= n) return;
    int lane = threadIdx.x & 63;
    int hb32 = lane & 32;                              // half base within wave
    int f = lane & 31;                                 // feature / column lane

    int4 c = hc[p];
    int key = ((c.x * 256 + c.y) * 256 + c.z) * 256 + c.w;
    int pk = ((hb[p] * 256 + c.y) * 256 + c.z) * 256 + c.w;

    // pool-side loads issued early (independent of probe chain)
    u64 pword = pool_bm[pk >> 6];
    u32 prank = pool_rank[pk >> 6];
    u64 mword = multi_bm[pk >> 6];

    // 9-lane probe: lane l = dt*3+dy owns the dz-triple [key-1, key+1]
    u32 bits = 0;
    float fv0 = 0.f, fv1 = 0.f, fv2 = 0.f;
    if (f < 9) {
        int t1 = f / 3, t2 = f - t1 * 3;
        int a = key + (t1 - 1) * 65536 + (t2 - 1) * 256 - 1;  // dz=-1 tap key
        int q = a >> 6, s = a & 63;
        u64 w0 = hist_bm[q];
        u64 w1 = 0;
        if (s >= 62) w1 = hist_bm[q + 1];              // rare window crossing
        u64 win = w0 >> s;
        if (s >= 62) win |= w1 << (64 - s);
        bits = (u32)win & 7u;
        if (bits) {                                    // hit taps only: rank+feat
#pragma unroll
            for (int j = 0; j < 3; j++) if ((bits >> j) & 1u) {
                int kj = a + j;
                int wq = kj >> 6, wb = kj & 63;
                u64 wd = (wq == q) ? w0 : w1;
                u32 r = hist_rank[wq] + (u32)__popcll(wd & ((1ull << wb) - 1ull));
                float v = hf[r];                       // rank == row index
                if (j == 0) fv0 = v; else if (j == 1) fv1 = v; else fv2 = v;
            }
        }
    }

    unsigned long long bal = __ballot(bits != 0);
    u32 lm = (u32)(bal >> hb32) & 0x1FFu;              // this half's hit lanes

    float acc = 0.f;
    while (lm) {                                       // uniform per half-wave
        int l = __ffs(lm) - 1;
        lm &= lm - 1;
        u32 b3 = (u32)__shfl((int)bits, hb32 + l);
#pragma unroll
        for (int j = 0; j < 3; j++) if ((b3 >> j) & 1u) {
            float fb = __shfl(j == 0 ? fv0 : j == 1 ? fv1 : fv2, hb32 + l);
            acc = fmaf(fb, Wbb[(l * 3 + j) * 32 + f], acc);  // L1-hot 3.4KB
        }
    }

    int bit = pk & 63;
    int slot = (int)(prank + (u32)__popcll(pword & ((1ull << bit) - 1ull)));
    bool multi = (mword >> bit) & 1ull;

    u32 tv = trans16(acc);
    u32 packed = tv | (((u32)__shfl_down((int)tv, 1)) << 16);  // pair (f, f+1)
    if ((f & 1) == 0) {
        u32* addr = pooled + (size_t)slot * 16 + (f >> 1);
        if (!multi) {
            *addr = packed;                            // ~99%: plain store
        } else {
            u32 oldv = *addr;
            while (true) {
                u32 lo = max(oldv & 0xFFFFu, packed & 0xFFFFu);
                u32 hi = max(oldv >> 16, packed >> 16);
                u32 mx = lo | (hi << 16);
                if (mx == oldv) break;
                u32 prev = atomicCAS(addr, oldv, mx);
                if (prev == oldv) break;
                oldv = prev;
            }
        }
    }
}

// K3: half-wave per query point: 27-tap conv (32->32) via 9-lane probe ------
__global__ void query_kernel(const int4* __restrict__ qc,
                             const float* __restrict__ pts,      // stride 5
                             const float* __restrict__ Wc,       // [27][32][32]
                             int m,
                             const u64* __restrict__ pool_bm,
                             const u32* __restrict__ pool_rank,
                             const u16* __restrict__ pooled16,
                             float* __restrict__ out) {
    int p = (blockIdx.x * blockDim.x + threadIdx.x) >> 5;
    if (p >= m) return;
    int lane = threadIdx.x & 63;
    int hb32 = lane & 32;
    int f = lane & 31;

    int4 c = qc[p];                                    // (b,x,y,z)
    int qk = ((c.x * 256 + c.y) * 256 + c.z) * 256 + c.w;

    u32 bits = 0;
    int sl0 = -1, sl1 = -1, sl2 = -1;
    if (f < 9) {
        int t1 = f / 3, t2 = f - t1 * 3;
        int a = qk + (t1 - 1) * 65536 + (t2 - 1) * 256 - 1;
        int q = a >> 6, s = a & 63;
        u64 w0 = pool_bm[q];                           // 4MB, L2-resident
        u64 w1 = 0;
        if (s >= 62) w1 = pool_bm[q + 1];
        u64 win = w0 >> s;
        if (s >= 62) win |= w1 << (64 - s);
        bits = (u32)win & 7u;
        if (bits) {                                    // ~6% of lanes
#pragma unroll
            for (int j = 0; j < 3; j++) if ((bits >> j) & 1u) {
                int kj = a + j;
                int wq = kj >> 6, wb = kj & 63;
                u64 wd = (wq == q) ? w0 : w1;
                int s_ = (int)(pool_rank[wq] +
                               (u32)__popcll(wd & ((1ull << wb) - 1ull)));
                if (j == 0) sl0 = s_; else if (j == 1) sl1 = s_; else sl2 = s_;
            }
        }
    }

    unsigned long long bal = __ballot(bits != 0);
    u32 lm = (u32)(bal >> hb32) & 0x1FFu;

    float acc = 0.f;
    while (lm) {                                       // uniform per half-wave
        int l = __ffs(lm) - 1;
        lm &= lm - 1;
        u32 b3 = (u32)__shfl((int)bits, hb32 + l);
#pragma unroll
        for (int j = 0; j < 3; j++) if ((b3 >> j) & 1u) {
            int slot = __shfl(j == 0 ? sl0 : j == 1 ? sl1 : sl2, hb32 + l);
            float pv = detrans16(pooled16[(size_t)slot * 32 + f]);  // 64B row
            const float* W = Wc + (l * 3 + j) * 1024 + f;  // W[b][k][f]
#pragma unroll
            for (int k = 0; k < 32; k++) {
                float pk_ = __shfl(pv, hb32 + k);      // broadcast P[k]
                acc = fmaf(pk_, W[k * 32], acc);       // coalesced 128B W line
            }
        }
    }

    out[(size_t)p * 36 + 4 + f] = acc;                 // features, coalesced
    if (f < 4) out[(size_t)p * 36 + f] = pts[p * 5 + f];  // head
}

// ---------------------------------------------------------------------------
extern "C" void kernel_launch(void* const* d_in, const int* in_sizes, int n_in,
                              void* d_out, int out_size, void* d_ws, size_t ws_size,
                              hipStream_t stream) {
    const float* hfeat   = (const float*)d_in[0];   // [n,1]
    const float* pts     = (const float*)d_in[1];   // [m,5]
    const float* Wbb     = (const float*)d_in[2];   // [27,1,32]
    const float* Wconv   = (const float*)d_in[3];   // [27,32,32]
    const int4*  hcoords = (const int4*)d_in[4];    // [n,4] sorted by packed key
    const int*   hbatch  = (const int*)d_in[5];     // [n]
    const int4*  qcoords = (const int4*)d_in[6];    // [m,4]
    int n = in_sizes[0];
    int m = in_sizes[1] / 5;

    const int NW_H = 1 << 22;                       // 2^28 bits / 64
    const int NW_P = 1 << 19;                       // 2^25 bits / 64
    const int GB_H = NW_H / (TPB * SCAN_WPT);       // 2048
    const int GB_P = NW_P / (TPB * SCAN_WPT);       // 256

    // layout: [hist_bm | pool_bm | multi_bm] zeroed; pooled NOT zeroed
    char* w = (char*)d_ws;
    char* zbase = w;
    u64* hist_bm      = (u64*)w;       w += (size_t)NW_H * 8;
    u64* pool_bm      = (u64*)w;       w += (size_t)NW_P * 8;
    u64* multi_bm     = (u64*)w;       w += (size_t)NW_P * 8;
    size_t zbytes = (size_t)(w - zbase);
    u32* pooled       = (u32*)w;       w += (size_t)n * 64;      // 16 u32/slot
    u32* hist_rank    = (u32*)w;       w += (size_t)NW_H * 4;
    u32* pool_rank    = (u32*)w;       w += (size_t)NW_P * 4;
    u32* bsum_h       = (u32*)w;       w += (size_t)GB_H * 4;
    u32* bsum_p       = (u32*)w;

    hipMemsetAsync(zbase, 0x00, zbytes, stream);

    int gb_n   = (n + TPB - 1) / TPB;
    int gb_n32 = (int)(((long long)n * 32 + TPB - 1) / TPB);
    int gb_m32 = (int)(((long long)m * 32 + TPB - 1) / TPB);

    build_bitmaps_kernel<<<gb_n, TPB, 0, stream>>>(hcoords, hbatch, n,
                                                   hist_bm, pool_bm, multi_bm);
    scan_sum_kernel<<<GB_H, TPB, 0, stream>>>(hist_bm, bsum_h);
    scan_partials_kernel<<<1, TPB, 0, stream>>>(bsum_h, GB_H);
    scan_apply_kernel<<<GB_H, TPB, 0, stream>>>(hist_bm, bsum_h, hist_rank);
    scan_sum_kernel<<<GB_P, TPB, 0, stream>>>(pool_bm, bsum_p);
    scan_partials_kernel<<<1, TPB, 0, stream>>>(bsum_p, GB_P);
    scan_apply_kernel<<<GB_P, TPB, 0, stream>>>(pool_bm, bsum_p, pool_rank);
    zero_multi_kernel<<<NW_P / TPB, TPB, 0, stream>>>(multi_bm, pool_bm,
                                                      pool_rank, pooled);
    bb_pool_kernel<<<gb_n32, TPB, 0, stream>>>(hcoords, hbatch, hfeat, Wbb, n,
                                               hist_bm, hist_rank,
                                               pool_bm, pool_rank, multi_bm, pooled);
    query_kernel<<<gb_m32, TPB, 0, stream>>>(qcoords, pts, Wconv, m,
                                             pool_bm, pool_rank,
                                             (const u16*)pooled, (float*)d_out);
}

// Round 2
// 359.135 us; speedup vs baseline: 1.0334x; 1.0334x over previous
//
#include <hip/hip_runtime.h>
#include <stdint.h>

// ---------------------------------------------------------------------------
// SparseResUQueryNet: bitmap+rank sparse conv -> time max-pool -> sparse conv
//
// Round-10 = round-8 skeleton + 9-lane PARALLEL probe + memset cut:
//   - 3x3x3 taps probed by 9 lanes (one per (dx,dy) column): ONE bm word +
//     ONE rank word (SAME index, loaded unconditionally IN PARALLEL — this
//     is what round-9 got wrong by serializing rank behind bm) cover the
//     dz in {-1,0,+1} bit-triple. Window crossing (s>=62, ~5%, address-only
//     condition) loads the q+1 pair, still parallel. Probe lane-requests
//     per point: 54 -> ~19, chain depth unchanged at 2 round-trips.
//   - query feature stores paired as float2 (32 -> 16 store lane-requests).
//   - pooled not memset (41MB): only multi-contributor slots need zero-init
//     for CAS-max; zero_multi_kernel handles those (verified round-9).
//   - everything else (split bm/rank, bf16 monotone-packed pooled, no query
//     sort, no LDS W staging, early pool-side loads) carried from round-8.
// ---------------------------------------------------------------------------

#define TPB 256
#define SCAN_WPT 8
typedef unsigned long long u64;
typedef unsigned int u32;
typedef unsigned short u16;

// f32 -> RNE bf16 -> monotone u16 (order-preserving; 0 is below all reals)
__device__ __forceinline__ u32 trans16(float x) {
    u32 b = __float_as_uint(x);
    u32 bf = (b + 0x7FFFu + ((b >> 16) & 1u)) >> 16;
    return ((bf & 0x8000u) ? (~bf) : (bf | 0x8000u)) & 0xFFFFu;
}
__device__ __forceinline__ float detrans16(u32 u) {
    u32 orig = (u & 0x8000u) ? (u & 0x7FFFu) : ((~u) & 0xFFFFu);
    return __uint_as_float(orig << 16);
}

// K1: set existence bits; second pool contributor marks multi ----------------
__global__ void build_bitmaps_kernel(const int4* __restrict__ hc,
                                     const int* __restrict__ hb,
                                     int n,
                                     u64* __restrict__ hist_bm,
                                     u64* __restrict__ pool_bm,
                                     u64* __restrict__ multi_bm) {
    int j = blockIdx.x * blockDim.x + threadIdx.x;
    if (j >= n) return;
    int4 c = hc[j];                                   // (t,x,y,z)
    int key = ((c.x * 256 + c.y) * 256 + c.z) * 256 + c.w;
    atomicOr(&hist_bm[key >> 6], 1ull << (key & 63));
    int pk = ((hb[j] * 256 + c.y) * 256 + c.z) * 256 + c.w;
    u64 bit = 1ull << (pk & 63);
    u64 old = atomicOr(&pool_bm[pk >> 6], bit);
    if (old & bit) atomicOr(&multi_bm[pk >> 6], bit); // >=2 contributors
}

// scan stage 1: per-block popcount sums --------------------------------------
__global__ void scan_sum_kernel(const u64* __restrict__ bm, u32* __restrict__ bsum) {
    __shared__ u32 s[TPB];
    int t = threadIdx.x;
    size_t base = ((size_t)blockIdx.x * TPB + t) * SCAN_WPT;
    u32 acc = 0;
#pragma unroll
    for (int i = 0; i < SCAN_WPT; i++) acc += __popcll(bm[base + i]);
    s[t] = acc; __syncthreads();
    for (int off = TPB / 2; off > 0; off >>= 1) {
        if (t < off) s[t] += s[t + off];
        __syncthreads();
    }
    if (t == 0) bsum[blockIdx.x] = s[0];
}

// scan stage 2: exclusive scan of block sums (count <= 2048), one block ------
__global__ void scan_partials_kernel(u32* __restrict__ bsum, int count) {
    __shared__ u32 s[TPB];
    int t = threadIdx.x;
    int wpt = count >> 8;                              // 8 (hist) or 1 (pool)
    u32 v[8]; u32 acc = 0;
    for (int i = 0; i < wpt; i++) { v[i] = bsum[t * wpt + i]; acc += v[i]; }
    s[t] = acc; __syncthreads();
    for (int off = 1; off < TPB; off <<= 1) {          // inclusive Hillis-Steele
        u32 x = (t >= off) ? s[t - off] : 0;
        __syncthreads();
        s[t] += x;
        __syncthreads();
    }
    u32 run = s[t] - acc;                              // exclusive base
    for (int i = 0; i < wpt; i++) { bsum[t * wpt + i] = run; run += v[i]; }
}

// scan stage 3: per-word exclusive rank --------------------------------------
__global__ void scan_apply_kernel(const u64* __restrict__ bm,
                                  const u32* __restrict__ bsum,
                                  u32* __restrict__ rank) {
    __shared__ u32 s[TPB];
    int t = threadIdx.x;
    size_t base = ((size_t)blockIdx.x * TPB + t) * SCAN_WPT;
    u32 pc[SCAN_WPT]; u32 acc = 0;
#pragma unroll
    for (int i = 0; i < SCAN_WPT; i++) { pc[i] = __popcll(bm[base + i]); acc += pc[i]; }
    s[t] = acc; __syncthreads();
    for (int off = 1; off < TPB; off <<= 1) {
        u32 x = (t >= off) ? s[t - off] : 0;
        __syncthreads();
        s[t] += x;
        __syncthreads();
    }
    u32 run = bsum[blockIdx.x] + s[t] - acc;
#pragma unroll
    for (int i = 0; i < SCAN_WPT; i++) { rank[base + i] = run; run += pc[i]; }
}

// zero only the pooled rows that will take the CAS-max path ------------------
__global__ void zero_multi_kernel(const u64* __restrict__ multi_bm,
                                  const u64* __restrict__ pool_bm,
                                  const u32* __restrict__ pool_rank,
                                  u32* __restrict__ pooled) {
    int wI = blockIdx.x * blockDim.x + threadIdx.x;    // word index < NW_P
    u64 mw = multi_bm[wI];
    if (!mw) return;
    u64 pw = pool_bm[wI];
    u32 rb = pool_rank[wI];
    while (mw) {
        int b = __ffsll((long long)mw) - 1;
        mw &= mw - 1;
        u32 slot = rb + (u32)__popcll(pw & ((1ull << b) - 1ull));
        u32* row = pooled + (size_t)slot * 16;
#pragma unroll
        for (int i = 0; i < 16; i++) row[i] = 0u;
    }
}

// K2: half-wave per voxel: 27-tap conv (1->32) via 9-lane parallel probe -----
__global__ void bb_pool_kernel(const int4* __restrict__ hc,
                               const int* __restrict__ hb,
                               const float* __restrict__ hf,
                               const float* __restrict__ Wbb,   // [27*32]
                               int n,
                               const u64* __restrict__ hist_bm,
                               const u32* __restrict__ hist_rank,
                               const u64* __restrict__ pool_bm,
                               const u32* __restrict__ pool_rank,
                               const u64* __restrict__ multi_bm,
                               u32* __restrict__ pooled) {
    int p = (blockIdx.x * blockDim.x + threadIdx.x) >> 5;   // voxel index
    if (p >= n) return;
    int lane = threadIdx.x & 63;
    int hb32 = lane & 32;                              // half base within wave
    int f = lane & 31;                                 // feature / column lane

    int4 c = hc[p];
    int key = ((c.x * 256 + c.y) * 256 + c.z) * 256 + c.w;
    int pk = ((hb[p] * 256 + c.y) * 256 + c.z) * 256 + c.w;

    // pool-side loads issued early (independent of probe chain)
    u64 pword = pool_bm[pk >> 6];
    u32 prank = pool_rank[pk >> 6];
    u64 mword = multi_bm[pk >> 6];

    // 9-lane probe: lane l = dx*3+dy owns the dz-triple [key-1, key+1].
    // bm[q] and rank[q] load in PARALLEL (independent addresses); the
    // crossing pair (q+1) is conditioned only on the ADDRESS (s>=62),
    // never on loaded data -> chain depth stays 1 round-trip here.
    u32 bits = 0;
    float fv0 = 0.f, fv1 = 0.f, fv2 = 0.f;
    if (f < 9) {
        int t1 = f / 3, t2 = f - t1 * 3;
        int a = key + (t1 - 1) * 65536 + (t2 - 1) * 256 - 1;  // dz=-1 tap key
        int q = a >> 6, s = a & 63;
        u64 w0 = hist_bm[q];
        u32 r0 = hist_rank[q];
        u64 w1 = 0; u32 r1 = 0;
        if (s >= 62) { w1 = hist_bm[q + 1]; r1 = hist_rank[q + 1]; }
        u64 win = w0 >> s;
        if (s >= 62) win |= w1 << (64 - s);
        bits = (u32)win & 7u;
        if (bits) {                                    // ~7%: feature loads
#pragma unroll
            for (int j = 0; j < 3; j++) if ((bits >> j) & 1u) {
                int kj = a + j;
                int wb = kj & 63;
                bool cr = (kj >> 6) != q;
                u64 wd = cr ? w1 : w0;
                u32 r = (cr ? r1 : r0) + (u32)__popcll(wd & ((1ull << wb) - 1ull));
                float v = hf[r];                       // rank == row index
                if (j == 0) fv0 = v; else if (j == 1) fv1 = v; else fv2 = v;
            }
        }
    }

    unsigned long long bal = __ballot(bits != 0);
    u32 lm = (u32)(bal >> hb32) & 0x1FFu;              // this half's hit lanes

    float acc = 0.f;
    while (lm) {                                       // uniform per half-wave
        int l = __ffs(lm) - 1;
        lm &= lm - 1;
        u32 b3 = (u32)__shfl((int)bits, hb32 + l);
#pragma unroll
        for (int j = 0; j < 3; j++) if ((b3 >> j) & 1u) {
            float fb = __shfl(j == 0 ? fv0 : j == 1 ? fv1 : fv2, hb32 + l);
            acc = fmaf(fb, Wbb[(l * 3 + j) * 32 + f], acc);  // L1-hot 3.4KB
        }
    }

    int bit = pk & 63;
    int slot = (int)(prank + (u32)__popcll(pword & ((1ull << bit) - 1ull)));
    bool multi = (mword >> bit) & 1ull;

    u32 tv = trans16(acc);
    u32 packed = tv | (((u32)__shfl_down((int)tv, 1)) << 16);  // pair (f, f+1)
    if ((f & 1) == 0) {
        u32* addr = pooled + (size_t)slot * 16 + (f >> 1);
        if (!multi) {
            *addr = packed;                            // ~99%: plain store
        } else {
            u32 oldv = *addr;
            while (true) {
                u32 lo = max(oldv & 0xFFFFu, packed & 0xFFFFu);
                u32 hi = max(oldv >> 16, packed >> 16);
                u32 mx = lo | (hi << 16);
                if (mx == oldv) break;
                u32 prev = atomicCAS(addr, oldv, mx);
                if (prev == oldv) break;
                oldv = prev;
            }
        }
    }
}

// K3: half-wave per query point: 27-tap conv (32->32), 9-lane parallel probe -
__global__ void query_kernel(const int4* __restrict__ qc,
                             const float* __restrict__ pts,      // stride 5
                             const float* __restrict__ Wc,       // [27][32][32]
                             int m,
                             const u64* __restrict__ pool_bm,
                             const u32* __restrict__ pool_rank,
                             const u16* __restrict__ pooled16,
                             float* __restrict__ out) {
    int p = (blockIdx.x * blockDim.x + threadIdx.x) >> 5;
    if (p >= m) return;
    int lane = threadIdx.x & 63;
    int hb32 = lane & 32;
    int f = lane & 31;

    int4 c = qc[p];                                    // (b,x,y,z)
    int qk = ((c.x * 256 + c.y) * 256 + c.z) * 256 + c.w;

    u32 bits = 0;
    int sl0 = 0, sl1 = 0, sl2 = 0;
    if (f < 9) {
        int t1 = f / 3, t2 = f - t1 * 3;
        int a = qk + (t1 - 1) * 65536 + (t2 - 1) * 256 - 1;
        int q = a >> 6, s = a & 63;
        u64 w0 = pool_bm[q];                           // 4MB, L2-resident
        u32 r0 = pool_rank[q];                         // 2MB, PARALLEL load
        u64 w1 = 0; u32 r1 = 0;
        if (s >= 62) { w1 = pool_bm[q + 1]; r1 = pool_rank[q + 1]; }
        u64 win = w0 >> s;
        if (s >= 62) win |= w1 << (64 - s);
        bits = (u32)win & 7u;
        if (bits) {                                    // slots: pure ALU now
#pragma unroll
            for (int j = 0; j < 3; j++) if ((bits >> j) & 1u) {
                int kj = a + j;
                int wb = kj & 63;
                bool cr = (kj >> 6) != q;
                u64 wd = cr ? w1 : w0;
                int s_ = (int)((cr ? r1 : r0) +
                               (u32)__popcll(wd & ((1ull << wb) - 1ull)));
                if (j == 0) sl0 = s_; else if (j == 1) sl1 = s_; else sl2 = s_;
            }
        }
    }

    unsigned long long bal = __ballot(bits != 0);
    u32 lm = (u32)(bal >> hb32) & 0x1FFu;

    float acc = 0.f;
    while (lm) {                                       // uniform per half-wave
        int l = __ffs(lm) - 1;
        lm &= lm - 1;
        u32 b3 = (u32)__shfl((int)bits, hb32 + l);
#pragma unroll
        for (int j = 0; j < 3; j++) if ((b3 >> j) & 1u) {
            int slot = __shfl(j == 0 ? sl0 : j == 1 ? sl1 : sl2, hb32 + l);
            float pv = detrans16(pooled16[(size_t)slot * 32 + f]);  // 64B row
            const float* W = Wc + (l * 3 + j) * 1024 + f;  // W[b][k][f]
#pragma unroll
            for (int k = 0; k < 32; k++) {
                float pk_ = __shfl(pv, hb32 + k);      // broadcast P[k]
                acc = fmaf(pk_, W[k * 32], acc);       // coalesced 128B W line
            }
        }
    }

    // paired float2 stores: 16 store lane-requests instead of 32
    float acc2 = __shfl_down(acc, 1);
    if ((f & 1) == 0) {
        float2 st; st.x = acc; st.y = acc2;
        *(float2*)(out + (size_t)p * 36 + 4 + f) = st;
    }
    if (f < 4) out[(size_t)p * 36 + f] = pts[p * 5 + f];  // head
}

// ---------------------------------------------------------------------------
extern "C" void kernel_launch(void* const* d_in, const int* in_sizes, int n_in,
                              void* d_out, int out_size, void* d_ws, size_t ws_size,
                              hipStream_t stream) {
    const float* hfeat   = (const float*)d_in[0];   // [n,1]
    const float* pts     = (const float*)d_in[1];   // [m,5]
    const float* Wbb     = (const float*)d_in[2];   // [27,1,32]
    const float* Wconv   = (const float*)d_in[3];   // [27,32,32]
    const int4*  hcoords = (const int4*)d_in[4];    // [n,4] sorted by packed key
    const int*   hbatch  = (const int*)d_in[5];     // [n]
    const int4*  qcoords = (const int4*)d_in[6];    // [m,4]
    int n = in_sizes[0];
    int m = in_sizes[1] / 5;

    const int NW_H = 1 << 22;                       // 2^28 bits / 64
    const int NW_P = 1 << 19;                       // 2^25 bits / 64
    const int GB_H = NW_H / (TPB * SCAN_WPT);       // 2048
    const int GB_P = NW_P / (TPB * SCAN_WPT);       // 256

    // layout: [hist_bm | pool_bm | multi_bm] zeroed; pooled NOT zeroed
    char* w = (char*)d_ws;
    char* zbase = w;
    u64* hist_bm      = (u64*)w;       w += (size_t)NW_H * 8;
    u64* pool_bm      = (u64*)w;       w += (size_t)NW_P * 8;
    u64* multi_bm     = (u64*)w;       w += (size_t)NW_P * 8;
    size_t zbytes = (size_t)(w - zbase);
    u32* pooled       = (u32*)w;       w += (size_t)n * 64;      // 16 u32/slot
    u32* hist_rank    = (u32*)w;       w += (size_t)NW_H * 4;
    u32* pool_rank    = (u32*)w;       w += (size_t)NW_P * 4;
    u32* bsum_h       = (u32*)w;       w += (size_t)GB_H * 4;
    u32* bsum_p       = (u32*)w;

    hipMemsetAsync(zbase, 0x00, zbytes, stream);

    int gb_n   = (n + TPB - 1) / TPB;
    int gb_n32 = (int)(((long long)n * 32 + TPB - 1) / TPB);
    int gb_m32 = (int)(((long long)m * 32 + TPB - 1) / TPB);

    build_bitmaps_kernel<<<gb_n, TPB, 0, stream>>>(hcoords, hbatch, n,
                                                   hist_bm, pool_bm, multi_bm);
    scan_sum_kernel<<<GB_H, TPB, 0, stream>>>(hist_bm, bsum_h);
    scan_partials_kernel<<<1, TPB, 0, stream>>>(bsum_h, GB_H);
    scan_apply_kernel<<<GB_H, TPB, 0, stream>>>(hist_bm, bsum_h, hist_rank);
    scan_sum_kernel<<<GB_P, TPB, 0, stream>>>(pool_bm, bsum_p);
    scan_partials_kernel<<<1, TPB, 0, stream>>>(bsum_p, GB_P);
    scan_apply_kernel<<<GB_P, TPB, 0, stream>>>(pool_bm, bsum_p, pool_rank);
    zero_multi_kernel<<<NW_P / TPB, TPB, 0, stream>>>(multi_bm, pool_bm,
                                                      pool_rank, pooled);
    bb_pool_kernel<<<gb_n32, TPB, 0, stream>>>(hcoords, hbatch, hfeat, Wbb, n,
                                               hist_bm, hist_rank,
                                               pool_bm, pool_rank, multi_bm, pooled);
    query_kernel<<<gb_m32, TPB, 0, stream>>>(qcoords, pts, Wconv, m,
                                             pool_bm, pool_rank,
                                             (const u16*)pooled, (float*)d_out);
}

// Round 3
// 283.636 us; speedup vs baseline: 1.3085x; 1.2662x over previous
//
#include <hip/hip_runtime.h>
#include <stdint.h>

// ---------------------------------------------------------------------------
// SparseResUQueryNet: bitmap+rank sparse conv -> time max-pool -> sparse conv
//
// Round-11 = EXACT round-8 hot-kernel structure (verified 285us, query 110us,
// VGPR 32, occupancy 67%) + occupancy-neutral deltas only:
//   - pooled (41MB) removed from memset; zero_multi_kernel zeroes only the
//     multi-contributor CAS-max rows (verified r9/r10).
//   - query feature stores paired as float2 (16 store lane-requests vs 32).
//   - __launch_bounds__(256,8) guards VGPR<=64 on hot kernels.
// Rounds 9/10 lesson: 9-lane probing doubled VGPR (32->60), halved occupancy
// (67->34%), and doubled time — probe-state must stay tiny. 27-lane probe
// with unconditional parallel bm+rank loads is the proven shape.
// ---------------------------------------------------------------------------

#define TPB 256
#define SCAN_WPT 8
typedef unsigned long long u64;
typedef unsigned int u32;
typedef unsigned short u16;

// f32 -> RNE bf16 -> monotone u16 (order-preserving; 0 is below all reals)
__device__ __forceinline__ u32 trans16(float x) {
    u32 b = __float_as_uint(x);
    u32 bf = (b + 0x7FFFu + ((b >> 16) & 1u)) >> 16;
    return ((bf & 0x8000u) ? (~bf) : (bf | 0x8000u)) & 0xFFFFu;
}
__device__ __forceinline__ float detrans16(u32 u) {
    u32 orig = (u & 0x8000u) ? (u & 0x7FFFu) : ((~u) & 0xFFFFu);
    return __uint_as_float(orig << 16);
}

// K1: set existence bits; second pool contributor marks multi ----------------
__global__ void build_bitmaps_kernel(const int4* __restrict__ hc,
                                     const int* __restrict__ hb,
                                     int n,
                                     u64* __restrict__ hist_bm,
                                     u64* __restrict__ pool_bm,
                                     u64* __restrict__ multi_bm) {
    int j = blockIdx.x * blockDim.x + threadIdx.x;
    if (j >= n) return;
    int4 c = hc[j];                                   // (t,x,y,z)
    int key = ((c.x * 256 + c.y) * 256 + c.z) * 256 + c.w;
    atomicOr(&hist_bm[key >> 6], 1ull << (key & 63));
    int pk = ((hb[j] * 256 + c.y) * 256 + c.z) * 256 + c.w;
    u64 bit = 1ull << (pk & 63);
    u64 old = atomicOr(&pool_bm[pk >> 6], bit);
    if (old & bit) atomicOr(&multi_bm[pk >> 6], bit); // >=2 contributors
}

// scan stage 1: per-block popcount sums --------------------------------------
__global__ void scan_sum_kernel(const u64* __restrict__ bm, u32* __restrict__ bsum) {
    __shared__ u32 s[TPB];
    int t = threadIdx.x;
    size_t base = ((size_t)blockIdx.x * TPB + t) * SCAN_WPT;
    u32 acc = 0;
#pragma unroll
    for (int i = 0; i < SCAN_WPT; i++) acc += __popcll(bm[base + i]);
    s[t] = acc; __syncthreads();
    for (int off = TPB / 2; off > 0; off >>= 1) {
        if (t < off) s[t] += s[t + off];
        __syncthreads();
    }
    if (t == 0) bsum[blockIdx.x] = s[0];
}

// scan stage 2: exclusive scan of block sums (count <= 2048), one block ------
__global__ void scan_partials_kernel(u32* __restrict__ bsum, int count) {
    __shared__ u32 s[TPB];
    int t = threadIdx.x;
    int wpt = count >> 8;                              // 8 (hist) or 1 (pool)
    u32 v[8]; u32 acc = 0;
    for (int i = 0; i < wpt; i++) { v[i] = bsum[t * wpt + i]; acc += v[i]; }
    s[t] = acc; __syncthreads();
    for (int off = 1; off < TPB; off <<= 1) {          // inclusive Hillis-Steele
        u32 x = (t >= off) ? s[t - off] : 0;
        __syncthreads();
        s[t] += x;
        __syncthreads();
    }
    u32 run = s[t] - acc;                              // exclusive base
    for (int i = 0; i < wpt; i++) { bsum[t * wpt + i] = run; run += v[i]; }
}

// scan stage 3: per-word exclusive rank --------------------------------------
__global__ void scan_apply_kernel(const u64* __restrict__ bm,
                                  const u32* __restrict__ bsum,
                                  u32* __restrict__ rank) {
    __shared__ u32 s[TPB];
    int t = threadIdx.x;
    size_t base = ((size_t)blockIdx.x * TPB + t) * SCAN_WPT;
    u32 pc[SCAN_WPT]; u32 acc = 0;
#pragma unroll
    for (int i = 0; i < SCAN_WPT; i++) { pc[i] = __popcll(bm[base + i]); acc += pc[i]; }
    s[t] = acc; __syncthreads();
    for (int off = 1; off < TPB; off <<= 1) {
        u32 x = (t >= off) ? s[t - off] : 0;
        __syncthreads();
        s[t] += x;
        __syncthreads();
    }
    u32 run = bsum[blockIdx.x] + s[t] - acc;
#pragma unroll
    for (int i = 0; i < SCAN_WPT; i++) { rank[base + i] = run; run += pc[i]; }
}

// zero only the pooled rows that will take the CAS-max path ------------------
__global__ void zero_multi_kernel(const u64* __restrict__ multi_bm,
                                  const u64* __restrict__ pool_bm,
                                  const u32* __restrict__ pool_rank,
                                  u32* __restrict__ pooled) {
    int wI = blockIdx.x * blockDim.x + threadIdx.x;    // word index < NW_P
    u64 mw = multi_bm[wI];
    if (!mw) return;
    u64 pw = pool_bm[wI];
    u32 rb = pool_rank[wI];
    while (mw) {
        int b = __ffsll((long long)mw) - 1;
        mw &= mw - 1;
        u32 slot = rb + (u32)__popcll(pw & ((1ull << b) - 1ull));
        u32* row = pooled + (size_t)slot * 16;
#pragma unroll
        for (int i = 0; i < 16; i++) row[i] = 0u;
    }
}

// K2: half-wave per voxel: 27-tap conv (1->32) + packed pooled write --------
__global__ __launch_bounds__(TPB, 8)
void bb_pool_kernel(const int4* __restrict__ hc,
                    const int* __restrict__ hb,
                    const float* __restrict__ hf,
                    const float* __restrict__ Wbb,   // [27*32]
                    int n,
                    const u64* __restrict__ hist_bm,
                    const u32* __restrict__ hist_rank,
                    const u64* __restrict__ pool_bm,
                    const u32* __restrict__ pool_rank,
                    const u64* __restrict__ multi_bm,
                    u32* __restrict__ pooled) {
    int p = (blockIdx.x * blockDim.x + threadIdx.x) >> 5;   // voxel index
    if (p >= n) return;
    int lane = threadIdx.x & 63;
    int hb32 = lane & 32;                              // half base within wave
    int f = lane & 31;                                 // feature / tap lane

    int4 c = hc[p];
    int key = ((c.x * 256 + c.y) * 256 + c.z) * 256 + c.w;
    int pk = ((hb[p] * 256 + c.y) * 256 + c.z) * 256 + c.w;

    // pool-side loads issued early (independent of probe chain)
    u64 pword = pool_bm[pk >> 6];
    u32 prank = pool_rank[pk >> 6];
    u64 mword = multi_bm[pk >> 6];

    float fv = 0.f;
    bool hit = false;
    if (f < 27) {
        int t1 = f / 9, rem = f - t1 * 9, t2 = rem / 3, t3 = rem - t2 * 3;
        int nk = key + (t1 - 1) * 65536 + (t2 - 1) * 256 + (t3 - 1);
        u64 word = hist_bm[nk >> 6];                   // parallel independent
        u32 rk   = hist_rank[nk >> 6];                 // loads (overlapped)
        if ((word >> (nk & 63)) & 1ull) {
            u32 r = rk + (u32)__popcll(word & ((1ull << (nk & 63)) - 1ull));
            fv = hf[r];                                // rank == row index j
            hit = true;
        }
    }
    unsigned long long bal = __ballot(hit);
    u32 mymask = (u32)(bal >> hb32);                   // this half's hit taps

    float acc = 0.f;
    while (mymask) {
        int b = __ffs(mymask) - 1;
        mymask &= mymask - 1;
        float fb = __shfl(fv, hb32 + b);               // broadcast neighbor feat
        acc = fmaf(fb, Wbb[b * 32 + f], acc);          // L1-hot 3.4KB table
    }

    int bit = pk & 63;
    int slot = (int)(prank + (u32)__popcll(pword & ((1ull << bit) - 1ull)));
    bool multi = (mword >> bit) & 1ull;

    u32 tv = trans16(acc);
    u32 packed = tv | (((u32)__shfl_down((int)tv, 1)) << 16);  // pair (f, f+1)
    if ((f & 1) == 0) {
        u32* addr = pooled + (size_t)slot * 16 + (f >> 1);
        if (!multi) {
            *addr = packed;                            // ~99%: plain store
        } else {
            u32 oldv = *addr;
            while (true) {
                u32 lo = max(oldv & 0xFFFFu, packed & 0xFFFFu);
                u32 hi = max(oldv >> 16, packed >> 16);
                u32 mx = lo | (hi << 16);
                if (mx == oldv) break;
                u32 prev = atomicCAS(addr, oldv, mx);
                if (prev == oldv) break;
                oldv = prev;
            }
        }
    }
}

// K3: half-wave per query point: 27-tap conv (32->32) + output --------------
__global__ __launch_bounds__(TPB, 8)
void query_kernel(const int4* __restrict__ qc,
                  const float* __restrict__ pts,      // stride 5
                  const float* __restrict__ Wc,       // [27][32][32]
                  int m,
                  const u64* __restrict__ pool_bm,
                  const u32* __restrict__ pool_rank,
                  const u16* __restrict__ pooled16,
                  float* __restrict__ out) {
    int p = (blockIdx.x * blockDim.x + threadIdx.x) >> 5;
    if (p >= m) return;
    int lane = threadIdx.x & 63;
    int hb32 = lane & 32;
    int f = lane & 31;

    int4 c = qc[p];                                    // (b,x,y,z)
    int qk = ((c.x * 256 + c.y) * 256 + c.z) * 256 + c.w;

    int slotL = -1;
    if (f < 27) {
        int t1 = f / 9, rem = f - t1 * 9, t2 = rem / 3, t3 = rem - t2 * 3;
        int nk = qk + (t1 - 1) * 65536 + (t2 - 1) * 256 + (t3 - 1);
        u64 word = pool_bm[nk >> 6];                   // 4MB, mostly L2
        u32 rk   = pool_rank[nk >> 6];                 // 2MB, parallel load
        if ((word >> (nk & 63)) & 1ull)
            slotL = (int)(rk + (u32)__popcll(word & ((1ull << (nk & 63)) - 1ull)));
    }
    unsigned long long bal = __ballot(slotL >= 0);
    u32 mymask = (u32)(bal >> hb32);

    float acc = 0.f;
    while (mymask) {
        int b = __ffs(mymask) - 1;                     // tap index
        mymask &= mymask - 1;
        int slot = __shfl(slotL, hb32 + b);
        float pv = detrans16(pooled16[(size_t)slot * 32 + f]);  // 64B row
        const float* W = Wc + b * 1024 + f;            // W[b][k][f], k-major
#pragma unroll
        for (int k = 0; k < 32; k++) {
            float pk_ = __shfl(pv, hb32 + k);          // broadcast P[k]
            acc = fmaf(pk_, W[k * 32], acc);           // coalesced 128B W line
        }
    }

    // paired float2 stores: 16 store lane-requests instead of 32
    float acc2 = __shfl_down(acc, 1);
    if ((f & 1) == 0) {
        float2 st; st.x = acc; st.y = acc2;
        *(float2*)(out + (size_t)p * 36 + 4 + f) = st;
    }
    if (f < 4) out[(size_t)p * 36 + f] = pts[p * 5 + f];  // head
}

// ---------------------------------------------------------------------------
extern "C" void kernel_launch(void* const* d_in, const int* in_sizes, int n_in,
                              void* d_out, int out_size, void* d_ws, size_t ws_size,
                              hipStream_t stream) {
    const float* hfeat   = (const float*)d_in[0];   // [n,1]
    const float* pts     = (const float*)d_in[1];   // [m,5]
    const float* Wbb     = (const float*)d_in[2];   // [27,1,32]
    const float* Wconv   = (const float*)d_in[3];   // [27,32,32]
    const int4*  hcoords = (const int4*)d_in[4];    // [n,4] sorted by packed key
    const int*   hbatch  = (const int*)d_in[5];     // [n]
    const int4*  qcoords = (const int4*)d_in[6];    // [m,4]
    int n = in_sizes[0];
    int m = in_sizes[1] / 5;

    const int NW_H = 1 << 22;                       // 2^28 bits / 64
    const int NW_P = 1 << 19;                       // 2^25 bits / 64
    const int GB_H = NW_H / (TPB * SCAN_WPT);       // 2048
    const int GB_P = NW_P / (TPB * SCAN_WPT);       // 256

    // layout: [hist_bm | pool_bm | multi_bm] zeroed; pooled NOT zeroed
    char* w = (char*)d_ws;
    char* zbase = w;
    u64* hist_bm      = (u64*)w;       w += (size_t)NW_H * 8;
    u64* pool_bm      = (u64*)w;       w += (size_t)NW_P * 8;
    u64* multi_bm     = (u64*)w;       w += (size_t)NW_P * 8;
    size_t zbytes = (size_t)(w - zbase);
    u32* pooled       = (u32*)w;       w += (size_t)n * 64;      // 16 u32/slot
    u32* hist_rank    = (u32*)w;       w += (size_t)NW_H * 4;
    u32* pool_rank    = (u32*)w;       w += (size_t)NW_P * 4;
    u32* bsum_h       = (u32*)w;       w += (size_t)GB_H * 4;
    u32* bsum_p       = (u32*)w;

    hipMemsetAsync(zbase, 0x00, zbytes, stream);

    int gb_n   = (n + TPB - 1) / TPB;
    int gb_n32 = (int)(((long long)n * 32 + TPB - 1) / TPB);
    int gb_m32 = (int)(((long long)m * 32 + TPB - 1) / TPB);

    build_bitmaps_kernel<<<gb_n, TPB, 0, stream>>>(hcoords, hbatch, n,
                                                   hist_bm, pool_bm, multi_bm);
    scan_sum_kernel<<<GB_H, TPB, 0, stream>>>(hist_bm, bsum_h);
    scan_partials_kernel<<<1, TPB, 0, stream>>>(bsum_h, GB_H);
    scan_apply_kernel<<<GB_H, TPB, 0, stream>>>(hist_bm, bsum_h, hist_rank);
    scan_sum_kernel<<<GB_P, TPB, 0, stream>>>(pool_bm, bsum_p);
    scan_partials_kernel<<<1, TPB, 0, stream>>>(bsum_p, GB_P);
    scan_apply_kernel<<<GB_P, TPB, 0, stream>>>(pool_bm, bsum_p, pool_rank);
    zero_multi_kernel<<<NW_P / TPB, TPB, 0, stream>>>(multi_bm, pool_bm,
                                                      pool_rank, pooled);
    bb_pool_kernel<<<gb_n32, TPB, 0, stream>>>(hcoords, hbatch, hfeat, Wbb, n,
                                               hist_bm, hist_rank,
                                               pool_bm, pool_rank, multi_bm, pooled);
    query_kernel<<<gb_m32, TPB, 0, stream>>>(qcoords, pts, Wconv, m,
                                             pool_bm, pool_rank,
                                             (const u16*)pooled, (float*)d_out);
}